// Round 1
// 311.388 us; speedup vs baseline: 1.1500x; 1.1500x over previous
//
#include <hip/hip_runtime.h>

typedef unsigned short ushort_t;
typedef float f32x4 __attribute__((ext_vector_type(4)));
typedef __bf16 bf16x8 __attribute__((ext_vector_type(8)));

#define PI2 6.283185307179586f
#define N_INNER_BLOCKS 256
#define N_INPUT_BLOCKS 3136

__device__ inline float fast_tanh(float x){
  float e = __expf(2.0f*x);
  return 1.0f - 2.0f/(e + 1.0f);
}

// Fused kernel.
//  blocks [0,256):      inner net.  block = (g, 16-wide i-tile). 4 waves, wave w owns
//                       i = i0+4w..i0+4w+3, all 256 j, full d (B-fragments computed in
//                       registers; no ff LDS staging). Coalesced 64B-line out0 writes.
//  blocks [256, 3392):  input net.  same structure as before but logits stay in f32
//                       registers (no bf16 sh_lg round-trip), cross-wave softmax via
//                       two 1KB LDS buffers, direct f32x4 stores, float4 weight loads,
//                       packed ds_write_b64 for hi staging.
__global__ __launch_bounds__(256, 3) void fused_kernel(
    const float* __restrict__ z,       // [256]
    const float* __restrict__ log_w,   // [256]
    const float* __restrict__ icoef,   // [2][32]
    const float* __restrict__ iw1,     // [1024][64]
    const float* __restrict__ iw2,     // [16][64]
    const float* __restrict__ ipc,     // [32]
    const float* __restrict__ nw1,     // [784][64][64]
    const float* __restrict__ nw2,     // [784][256][64]
    float* __restrict__ out0,          // [16][256 j][256 i]
    float* __restrict__ out1)          // [784][256 n][256 c]
{
  // union'd LDS: inner uses res[16][260]+zz+lw (18.6KB); input uses fB+hB+wred+sred (18KB)
  __shared__ __align__(16) char smem[18688];
  const int tx   = threadIdx.x;
  const int lane = tx & 63, w = tx >> 6;
  const int q    = lane >> 4, l15 = lane & 15;

  if (blockIdx.x < N_INNER_BLOCKS){
    // ============================ inner net ============================
    const int ib = blockIdx.x;
    const int g  = ib >> 4;
    const int i0 = (ib & 15) << 4;

    float* res = (float*)smem;                  // [16][260] f32 (pad 260 vs bank)
    float* zz  = (float*)(smem + 16640);        // [256]
    float* lwv = (float*)(smem + 17664);        // [256]

    zz[tx]  = z[tx];
    lwv[tx] = log_w[tx];
    __syncthreads();

    // per-lane fourier coefficients (k = 8q+ii)
    float cA[8], cB[8];
    #pragma unroll
    for (int ii = 0; ii < 8; ii++){
      cA[ii] = PI2 * icoef[8*q + ii];
      cB[ii] = PI2 * icoef[32 + 8*q + ii];
    }

    // A fragments for all 4 d-tiles: rows d = 16dt + l15, k = 8q+ii (+32 for A1)
    bf16x8 A0[4], A1[4];
    #pragma unroll
    for (int dt = 0; dt < 4; dt++){
      const float* Ar = iw1 + (size_t)(g*64 + 16*dt + l15)*64 + 8*q;
      f32x4 a0 = *(const f32x4*)Ar;
      f32x4 a1 = *(const f32x4*)(Ar + 4);
      f32x4 a2 = *(const f32x4*)(Ar + 32);
      f32x4 a3 = *(const f32x4*)(Ar + 36);
      #pragma unroll
      for (int ii = 0; ii < 4; ii++){
        A0[dt][ii]   = (__bf16)a0[ii];
        A0[dt][4+ii] = (__bf16)a1[ii];
        A1[dt][ii]   = (__bf16)a2[ii];
        A1[dt][4+ii] = (__bf16)a3[ii];
      }
    }
    f32x4 w2v[4];   // w2[g][16dt + 4q + r]
    #pragma unroll
    for (int dt = 0; dt < 4; dt++)
      w2v[dt] = *(const f32x4*)(iw2 + g*64 + 16*dt + 4*q);

    #pragma unroll 1
    for (int il = 0; il < 4; il++){
      const int irow = 4*w + il;              // local i index 0..15
      const float zi = zz[i0 + irow];
      float xA[8];
      #pragma unroll
      for (int ii = 0; ii < 8; ii++) xA[ii] = zi * cA[ii];

      float m = -3.0e38f;
      #pragma unroll 2
      for (int jt = 0; jt < 16; jt++){
        const float zj = zz[16*jt + l15];     // column j = 16jt + l15
        bf16x8 B0, B1;
        #pragma unroll
        for (int ii = 0; ii < 8; ii++){
          float sv, cv;
          __sincosf(xA[ii] + zj*cB[ii], &sv, &cv);
          B0[ii] = (__bf16)cv;                // ff rows 0..31  = cos
          B1[ii] = (__bf16)sv;                // ff rows 32..63 = sin
        }
        float p = 0.f;
        #pragma unroll
        for (int dt = 0; dt < 4; dt++){
          f32x4 acc = {0.f, 0.f, 0.f, 0.f};
          acc = __builtin_amdgcn_mfma_f32_16x16x32_bf16(A0[dt], B0, acc, 0, 0, 0);
          acc = __builtin_amdgcn_mfma_f32_16x16x32_bf16(A1[dt], B1, acc, 0, 0, 0);
          p = fmaf(w2v[dt][0], fast_tanh(acc[0]), p);
          p = fmaf(w2v[dt][1], fast_tanh(acc[1]), p);
          p = fmaf(w2v[dt][2], fast_tanh(acc[2]), p);
          p = fmaf(w2v[dt][3], fast_tanh(acc[3]), p);
        }
        // sum the 4 k-quadrant partials (all lanes end with full y)
        p += __shfl_xor(p, 16, 64);
        p += __shfl_xor(p, 32, 64);
        float sp = fmaxf(p, 0.f) + __logf(1.f + __expf(-fabsf(p)));
        float tval = -sp + lwv[16*jt + l15];  // logit + log_w[j]
        if (q == 0) res[irow*260 + 16*jt + l15] = tval;
        m = fmaxf(m, tval);
      }
      // softmax over all 256 j (within 16-lane group; q groups are duplicates)
      #pragma unroll
      for (int o = 1; o < 16; o <<= 1) m = fmaxf(m, __shfl_xor(m, o, 64));
      float s = 0.f;
      #pragma unroll
      for (int jt = 0; jt < 16; jt++)
        s += __expf(res[irow*260 + 16*jt + l15] - m);
      #pragma unroll
      for (int o = 1; o < 16; o <<= 1) s += __shfl_xor(s, o, 64);
      const float lse = m + __logf(s);
      if (q == 0){
        #pragma unroll
        for (int jt = 0; jt < 16; jt++){
          const int idx = irow*260 + 16*jt + l15;
          res[idx] = __expf(res[idx] - lse);
        }
      }
    }
    __syncthreads();
    // coalesced out0 write: 4 lanes cover one full 64B line per j-row
    {
      const int j2 = tx >> 2, c4 = tx & 3;
      const size_t base = (size_t)g*65536 + (size_t)i0 + 4*c4;
      #pragma unroll
      for (int it2 = 0; it2 < 4; it2++){
        const int j = 64*it2 + j2;
        f32x4 v;
        #pragma unroll
        for (int rr = 0; rr < 4; rr++) v[rr] = res[(4*c4 + rr)*260 + j];
        *(f32x4*)(out0 + base + (size_t)j*256) = v;
      }
    }
  } else {
    // ============================ input net ============================
    const int b   = blockIdx.x - N_INNER_BLOCKS;
    const int xcd = b & 7;
    const int s5  = b >> 3;
    const int g   = xcd*98 + (s5 >> 2);       // 4 consecutive slots -> same g, same XCD
    const int nt  = s5 & 3;

    __bf16* fB   = (__bf16*)smem;             // ffi B-frags, 8 KB
    __bf16* hB   = (__bf16*)(smem + 8192);    // hi  B-frags, 8 KB
    float*  wred = (float*)(smem + 16384);    // [4][64] wave maxes
    float*  sred = (float*)(smem + 17408);    // [4][64] wave sums

    // ---- phase 0: ffi packed into B-fragment layout ----
    {
      const int n = tx & 63, qq = tx >> 6;
      const int t = n >> 4, nn = n & 15;
      const float zn = z[nt*64 + n];
      union { __bf16 h[8]; uint4 v; } pc, ps;
      #pragma unroll
      for (int ii = 0; ii < 8; ii++){
        float sv, cv;
        __sincosf(PI2 * zn * ipc[8*qq + ii], &sv, &cv);
        pc.h[ii] = (__bf16)cv;
        ps.h[ii] = (__bf16)sv;
      }
      ((uint4*)fB)[(t*2+0)*64 + 16*qq + nn] = pc.v;
      ((uint4*)fB)[(t*2+1)*64 + 16*qq + nn] = ps.v;
    }
    __syncthreads();

    // ---- phase 1: hi = tanh(W1g @ ffi), wave w -> d-tile [16w,16w+16) ----
    {
      const float* Ar = nw1 + (size_t)g*4096 + (size_t)(16*w + l15)*64 + 8*q;
      f32x4 a0 = *(const f32x4*)Ar;
      f32x4 a1 = *(const f32x4*)(Ar + 4);
      f32x4 a2 = *(const f32x4*)(Ar + 32);
      f32x4 a3 = *(const f32x4*)(Ar + 36);
      bf16x8 A0, A1;
      #pragma unroll
      for (int ii = 0; ii < 4; ii++){
        A0[ii] = (__bf16)a0[ii];  A0[4+ii] = (__bf16)a1[ii];
        A1[ii] = (__bf16)a2[ii];  A1[4+ii] = (__bf16)a3[ii];
      }
      // acc rows d = 16w+4q+r have consecutive iB = 4(q&1)+r -> one b64 write
      const int dlt = w >> 1;
      const int qB  = 2*(w & 1) + (q >> 1);
      const int iB0 = 4*(q & 1);
      #pragma unroll
      for (int t = 0; t < 4; t++){
        bf16x8 B0 = *(const bf16x8*)(fB + ((t*2+0)*64 + lane)*8);
        bf16x8 B1 = *(const bf16x8*)(fB + ((t*2+1)*64 + lane)*8);
        f32x4 acc = {0.f, 0.f, 0.f, 0.f};
        acc = __builtin_amdgcn_mfma_f32_16x16x32_bf16(A0, B0, acc, 0, 0, 0);
        acc = __builtin_amdgcn_mfma_f32_16x16x32_bf16(A1, B1, acc, 0, 0, 0);
        union { __bf16 h[4]; uint2 v; } pk;
        #pragma unroll
        for (int r = 0; r < 4; r++) pk.h[r] = (__bf16)fast_tanh(acc[r]);
        *(uint2*)(hB + ((size_t)(t*2+dlt)*64 + qB*16 + l15)*8 + iB0) = pk.v;
      }
    }
    __syncthreads();

    // ---- phase 2: logits in registers. wave w -> c in [64w, 64w+64) ----
    // lg[cc][t][r]: c = 64w + 16cc + 4q + r, n = 16t + l15
    float lg[4][4][4];
    {
      const float* w2g = nw2 + (size_t)g*16384;
      #pragma unroll
      for (int cc = 0; cc < 4; cc++){
        const float* Ar = w2g + (size_t)(16*(4*w + cc) + l15)*64 + 8*q;
        f32x4 a0 = *(const f32x4*)Ar;
        f32x4 a1 = *(const f32x4*)(Ar + 4);
        f32x4 a2 = *(const f32x4*)(Ar + 32);
        f32x4 a3 = *(const f32x4*)(Ar + 36);
        bf16x8 A0, A1;
        #pragma unroll
        for (int ii = 0; ii < 4; ii++){
          A0[ii] = (__bf16)a0[ii];  A0[4+ii] = (__bf16)a1[ii];
          A1[ii] = (__bf16)a2[ii];  A1[4+ii] = (__bf16)a3[ii];
        }
        #pragma unroll
        for (int t = 0; t < 4; t++){
          bf16x8 B0 = *(const bf16x8*)(hB + ((t*2+0)*64 + lane)*8);
          bf16x8 B1 = *(const bf16x8*)(hB + ((t*2+1)*64 + lane)*8);
          f32x4 acc = {0.f, 0.f, 0.f, 0.f};
          acc = __builtin_amdgcn_mfma_f32_16x16x32_bf16(A0, B0, acc, 0, 0, 0);
          acc = __builtin_amdgcn_mfma_f32_16x16x32_bf16(A1, B1, acc, 0, 0, 0);
          #pragma unroll
          for (int r = 0; r < 4; r++) lg[cc][t][r] = acc[r];
        }
      }
    }

    // ---- phase 3: cross-wave log_softmax over c, from registers ----
    float lsev[4];
    #pragma unroll
    for (int t = 0; t < 4; t++){
      float mt = lg[0][t][0];
      #pragma unroll
      for (int cc = 0; cc < 4; cc++){
        #pragma unroll
        for (int r = 0; r < 4; r++) mt = fmaxf(mt, lg[cc][t][r]);
      }
      mt = fmaxf(mt, __shfl_xor(mt, 16, 64));
      mt = fmaxf(mt, __shfl_xor(mt, 32, 64));
      if (q == 0) wred[w*64 + 16*t + l15] = mt;
    }
    __syncthreads();
    #pragma unroll
    for (int t = 0; t < 4; t++){
      const int nn = 16*t + l15;
      float M = fmaxf(fmaxf(wred[nn], wred[64+nn]), fmaxf(wred[128+nn], wred[192+nn]));
      float st = 0.f;
      #pragma unroll
      for (int cc = 0; cc < 4; cc++){
        #pragma unroll
        for (int r = 0; r < 4; r++) st += __expf(lg[cc][t][r] - M);
      }
      st += __shfl_xor(st, 16, 64);
      st += __shfl_xor(st, 32, 64);
      if (q == 0) sred[w*64 + 16*t + l15] = st;
      lsev[t] = M;                       // stash global max
    }
    __syncthreads();
    #pragma unroll
    for (int t = 0; t < 4; t++){
      const int nn = 16*t + l15;
      float S = sred[nn] + sred[64+nn] + sred[128+nn] + sred[192+nn];
      lsev[t] = lsev[t] + __logf(S);
    }

    // ---- stores: f32x4, 4 q-lanes fill each 64B line ----
    {
      const size_t base = (size_t)g*65536 + (size_t)(nt*64)*256 + (size_t)(64*w);
      #pragma unroll
      for (int t = 0; t < 4; t++){
        const size_t rowb = base + (size_t)(16*t + l15)*256;
        #pragma unroll
        for (int cc = 0; cc < 4; cc++){
          f32x4 v;
          #pragma unroll
          for (int r = 0; r < 4; r++) v[r] = lg[cc][t][r] - lsev[t];
          *(f32x4*)(out1 + rowb + 16*cc + 4*q) = v;
        }
      }
    }
  }
}

extern "C" void kernel_launch(void* const* d_in, const int* in_sizes, int n_in,
                              void* d_out, int out_size, void* d_ws, size_t ws_size,
                              hipStream_t stream)
{
  const float* z     = (const float*)d_in[0];
  const float* lw    = (const float*)d_in[1];
  const float* icoef = (const float*)d_in[2];
  const float* iw1   = (const float*)d_in[3];
  const float* iw2   = (const float*)d_in[4];
  const float* ipc   = (const float*)d_in[5];
  const float* inw1  = (const float*)d_in[6];
  const float* inw2  = (const float*)d_in[7];

  float* out0 = (float*)d_out;
  float* out1 = out0 + (size_t)16*256*256;

  hipLaunchKernelGGL(fused_kernel, dim3(N_INNER_BLOCKS + N_INPUT_BLOCKS), dim3(256), 0, stream,
                     z, lw, icoef, iw1, iw2, ipc, inw1, inw2, out0, out1);
}